// Round 5
// baseline (267.682 us; speedup 1.0000x reference)
//
#include <hip/hip_runtime.h>
#include <math.h>

typedef _Float16 f16;
typedef _Float16 half8 __attribute__((ext_vector_type(8)));
typedef float floatx16 __attribute__((ext_vector_type(16)));

#define HW_     3136
#define NPC     50176.0f
#define PB      3364            // 58*58 padded pixels per image
#define PPLANE  53824           // 16 images * PB (chunks per k2-plane)
#define ASTRIDE ((size_t)2 * PPLANE * 16)   // bytes between s-steps (k2 += 2)

// LDS rotation swizzle (used by final_kernel only): conflict-free for both
// (c fixed, px varies) and (px fixed, c varies with stride 4) patterns.
#define SW(c, px) (((px) + ((c) >> 2) + ((c) & 3) * 8) & 63)

// ---------------------------------------------------------------------------
// prep: quantize weights to integer-valued fp16 and pack MFMA-fragment-major:
// W2[(tap*16 + k2)*128 + oc] = 8 f16 chunk of channels k2*8..k2*8+7
// ---------------------------------------------------------------------------
__global__ __launch_bounds__(256) void prep_kernel(
        const float* __restrict__ w1, const float* __restrict__ wa1,
        const float* __restrict__ w2, const float* __restrict__ wa2,
        f16* __restrict__ W2a, f16* __restrict__ W2b) {
    const int idx = blockIdx.x * 256 + threadIdx.x;    // 0..36863
    const float* w;
    const float* wa;
    f16* o;
    int m;
    if (idx < 18432) { w = w1; wa = wa1; o = W2a; m = idx; }
    else             { w = w2; wa = wa2; o = W2b; m = idx - 18432; }
    const int tap = m >> 11;
    const int r = m & 2047;
    const int k2 = r >> 7;
    const int oc = r & 127;
    const float a = wa[tap];
    const float* src = w + ((size_t)(tap * 128 + oc) * 128 + k2 * 8);
    half8 hv;
#pragma unroll
    for (int j = 0; j < 8; ++j)
        hv[j] = (f16)rintf(fminf(fmaxf(src[j] / a, -4.f), 3.f));
    *(half8*)(o + (size_t)m * 8) = hv;
}

// ---------------------------------------------------------------------------
// pad: zero the spatial border chunks of X2 (all 32 k2-planes, 16 images)
// ---------------------------------------------------------------------------
__global__ __launch_bounds__(256) void pad_kernel(char* __restrict__ X2) {
    const int idx = blockIdx.x * 256 + threadIdx.x;    // 116736 = 32*16*228
    const int k2 = idx / 3648;
    const int r = idx - k2 * 3648;
    const int b = r / 228;
    const int j = r - b * 228;
    int h, w;
    if (j < 58)        { h = 0;  w = j; }
    else if (j < 116)  { h = 57; w = j - 58; }
    else { const int k = j - 116; h = 1 + (k >> 1); w = (k & 1) * 57; }
    const size_t chunk = (size_t)k2 * PPLANE + (size_t)b * PB + h * 58 + w;
    float4 z = {0.f, 0.f, 0.f, 0.f};
    *(float4*)(X2 + chunk * 16) = z;
}

// ---------------------------------------------------------------------------
// pack: x fp32 [b][c][hw] -> X2 hi/lo fp16 chunks [k2][b][hp][wp].
// LDS-free: thread = (cg, 4-px group); register transpose of an 8x4 tile.
// ---------------------------------------------------------------------------
__global__ __launch_bounds__(256) void pack_kernel(
        const float* __restrict__ x, char* __restrict__ X2,
        float* __restrict__ stats) {
    const int t = threadIdx.x;
    if (blockIdx.x == 0 && t < 512) stats[t] = 0.f;    // zero stats1+stats2
    const int idx = blockIdx.x * 256 + t;              // 200704
    const int cg = idx / 12544;                        // 0..15
    const int pg = idx - cg * 12544;                   // 4-px group
    const int p  = pg * 4;                             // global pixel
    const int b  = p / HW_;
    const int pi = p - b * HW_;
    float v[8][4];
    const float* xb = x + (size_t)(b * 128 + cg * 8) * HW_ + pi;
#pragma unroll
    for (int j = 0; j < 8; ++j) {
        const float4 t4 = *(const float4*)(xb + (size_t)j * HW_);
        v[j][0] = t4.x; v[j][1] = t4.y; v[j][2] = t4.z; v[j][3] = t4.w;
    }
#pragma unroll
    for (int i = 0; i < 4; ++i) {
        const int pp = pi + i;
        const int h = pp / 56;
        const int w = pp - h * 56;
        const size_t chunk = (size_t)b * PB + (h + 1) * 58 + (w + 1);
        half8 hv, lv;
#pragma unroll
        for (int j = 0; j < 8; ++j) {
            const float val = v[j][i];
            const f16 hh = (f16)val;
            hv[j] = hh;
            lv[j] = (f16)(val - (float)hh);
        }
        *(half8*)(X2 + ((size_t)cg * PPLANE + chunk) * 16) = hv;
        *(half8*)(X2 + ((size_t)(cg + 16) * PPLANE + chunk) * 16) = lv;
    }
}

// ---------------------------------------------------------------------------
// conv: barrier-free MFMA split-conv with CROSS-TAP software pipeline.
// Block = 128px x 128oc, 4 waves 64x64. B fragments overwritten in place
// right after last use (8-step lookahead); A rotation refills from next tap
// during s in [12,16). No __syncthreads in the main loop.
// ---------------------------------------------------------------------------
__global__ __launch_bounds__(256, 2) void conv_kernel(
        const char* __restrict__ X2, const char* __restrict__ W2,
        const float* __restrict__ wav, const float* __restrict__ pav,
        float* __restrict__ cbuf, float* __restrict__ stats) {
    __shared__ float red[512];
    const int t = threadIdx.x;
    const int lane = t & 63;
    const int wv = t >> 6;
    const int wm = wv & 1, wn = wv >> 1;
    const int tile = (blockIdx.x & 7) * 49 + (blockIdx.x >> 3);  // XCD swizzle
    const int kh = lane >> 5;
    const int ln = lane & 31;

    int ppad[2];
#pragma unroll
    for (int mt = 0; mt < 2; ++mt) {
        const int gp = tile * 128 + wm * 64 + mt * 32 + ln;
        const int b = gp / HW_;
        const int p = gp - b * HW_;
        const int h = p / 56;
        const int w = p - h * 56;
        ppad[mt] = b * PB + (h + 1) * 58 + (w + 1);
    }
    int bb2[2];
#pragma unroll
    for (int nt = 0; nt < 2; ++nt)
        bb2[nt] = (kh * 128 + wn * 64 + nt * 32 + ln) * 16;

    floatx16 facc[2][2];
#pragma unroll
    for (int mt = 0; mt < 2; ++mt)
#pragma unroll
        for (int nt = 0; nt < 2; ++nt)
#pragma unroll
            for (int r = 0; r < 16; ++r) facc[mt][nt][r] = 0.f;

    // ---- prologue: tap 0 addresses + initial A/B fragment fill ----
    size_t aoff[2], aoffn[2];
#pragma unroll
    for (int mt = 0; mt < 2; ++mt)
        aoff[mt] = ((size_t)(ppad[mt] + (-1) * 58 + (-1)) + (size_t)kh * PPLANE) * 16;

    half8 afr[2][4];
#pragma unroll
    for (int s0 = 0; s0 < 4; ++s0)
#pragma unroll
        for (int mt = 0; mt < 2; ++mt)
            afr[mt][s0] = *(const half8*)(X2 + aoff[mt] + (size_t)s0 * ASTRIDE);

    half8 bfr[2][8];
#pragma unroll
    for (int nt = 0; nt < 2; ++nt)
#pragma unroll
        for (int kf = 0; kf < 8; ++kf)
            bfr[nt][kf] = *(const half8*)(W2 + bb2[nt] + kf * 4096);

#pragma unroll
    for (int tap = 0; tap < 9; ++tap) {
        const float pak = pav[tap];
        const float s1 = wav[tap] / pak;
        if (tap < 8) {
            const int din = (tap + 1) % 3 - 1;
            const int djn = (tap + 1) / 3 - 1;
            const int dn = din * 58 + djn;
#pragma unroll
            for (int mt = 0; mt < 2; ++mt)
                aoffn[mt] = ((size_t)(ppad[mt] + dn) + (size_t)kh * PPLANE) * 16;
        }
        const char* wtn = W2 + (tap + 1) * 32768;

        floatx16 acc[2][2];
#pragma unroll
        for (int mt = 0; mt < 2; ++mt)
#pragma unroll
            for (int nt = 0; nt < 2; ++nt)
#pragma unroll
                for (int r = 0; r < 16; ++r) acc[mt][nt][r] = 0.f;

#pragma unroll
        for (int s = 0; s < 16; ++s) {
#pragma unroll
            for (int nt = 0; nt < 2; ++nt)
#pragma unroll
                for (int mt = 0; mt < 2; ++mt)
                    acc[mt][nt] = __builtin_amdgcn_mfma_f32_32x32x16_f16(
                        afr[mt][s & 3], bfr[nt][s & 7], acc[mt][nt], 0, 0, 0);
            // A refill: within-tap for s<12, next tap's chunks 0..3 for s>=12
            if (s < 12) {
#pragma unroll
                for (int mt = 0; mt < 2; ++mt)
                    afr[mt][s & 3] =
                        *(const half8*)(X2 + aoff[mt] + (size_t)(s + 4) * ASTRIDE);
            } else if (tap < 8) {
#pragma unroll
                for (int mt = 0; mt < 2; ++mt)
                    afr[mt][s & 3] =
                        *(const half8*)(X2 + aoffn[mt] + (size_t)(s - 12) * ASTRIDE);
            }
            // B refill in place right after last use (bfr[.][kf] dead after s=8+kf)
            if (tap < 8 && s >= 8) {
                const int kf = s - 8;
#pragma unroll
                for (int nt = 0; nt < 2; ++nt)
                    bfr[nt][kf] = *(const half8*)(wtn + bb2[nt] + kf * 4096);
            }
        }

        // per-tap 8-bit LSQ quantize of the partial sum, accumulate
#pragma unroll
        for (int mt = 0; mt < 2; ++mt)
#pragma unroll
            for (int nt = 0; nt < 2; ++nt)
#pragma unroll
                for (int r = 0; r < 16; ++r) {
                    const float q =
                        rintf(fminf(fmaxf(acc[mt][nt][r] * s1, -128.f), 127.f));
                    facc[mt][nt][r] = fmaf(q, pak, facc[mt][nt][r]);
                }
        aoff[0] = aoffn[0];
        aoff[1] = aoffn[1];
    }

    // epilogue: cbuf [gp][oc] fp32   (32x32 C/D: row=(r&3)+8*(r>>2)+4*kh, col=ln)
    const int gpb = tile * 128 + wm * 64;
    const int ocb = wn * 64 + ln;
#pragma unroll
    for (int mt = 0; mt < 2; ++mt)
#pragma unroll
        for (int r = 0; r < 16; ++r) {
            const int row = (r & 3) + 8 * (r >> 2) + 4 * kh;
            const int gp = gpb + mt * 32 + row;
            float* rp = cbuf + (size_t)gp * 128 + ocb;
            rp[0]  = facc[mt][0][r];
            rp[32] = facc[mt][1][r];
        }

    // fused BN stats
    float sv[2], qv[2];
#pragma unroll
    for (int nt = 0; nt < 2; ++nt) {
        float s = 0.f, q = 0.f;
#pragma unroll
        for (int mt = 0; mt < 2; ++mt)
#pragma unroll
            for (int r = 0; r < 16; ++r) {
                const float v = facc[mt][nt][r];
                s += v;
                q = fmaf(v, v, q);
            }
        s += __shfl_xor(s, 32, 64);
        q += __shfl_xor(q, 32, 64);
        sv[nt] = s; qv[nt] = q;
    }
    if (lane < 32) {
#pragma unroll
        for (int nt = 0; nt < 2; ++nt) {
            const int oc = wn * 64 + nt * 32 + lane;
            red[oc * 2 + wm] = sv[nt];
            red[256 + oc * 2 + wm] = qv[nt];
        }
    }
    __syncthreads();
    if (t < 128) {
        atomicAdd(&stats[t],       red[2 * t] + red[2 * t + 1]);
        atomicAdd(&stats[128 + t], red[256 + 2 * t] + red[256 + 2 * t + 1]);
    }
}

// ---------------------------------------------------------------------------
// bn_split: cbuf fp32 [gp][oc] -> bn+relu -> X2 hi/lo packed (conv2 input).
// LDS-free: thread = (4-px group, cg); lanes are cg-minor for coalesced reads.
// ---------------------------------------------------------------------------
__global__ __launch_bounds__(256) void bn_split_kernel(
        const float* __restrict__ cbuf, const float* __restrict__ stats,
        const float* __restrict__ g, const float* __restrict__ bb,
        char* __restrict__ X2) {
    __shared__ float scs[128], shs[128];
    const int t = threadIdx.x;
    if (t < 128) {
        const float m = stats[t] * (1.f / NPC);
        const float var = stats[128 + t] * (1.f / NPC) - m * m;
        const float inv = 1.f / sqrtf(var + 1e-5f);
        const float sc = g[t] * inv;
        scs[t] = sc;
        shs[t] = bb[t] - m * sc;
    }
    __syncthreads();
    const int idx = blockIdx.x * 256 + t;    // 200704
    const int pg = idx >> 4;                 // 4-px group (global pixel/4)
    const int cg = idx & 15;                 // oc chunk
    const int p = pg * 4;
    const int b = p / HW_;
    const int pi = p - b * HW_;
    const float4 s0 = *(const float4*)&scs[cg * 8];
    const float4 s1 = *(const float4*)&scs[cg * 8 + 4];
    const float4 h0 = *(const float4*)&shs[cg * 8];
    const float4 h1 = *(const float4*)&shs[cg * 8 + 4];
#pragma unroll
    for (int i = 0; i < 4; ++i) {
        const float4 va = *(const float4*)&cbuf[(size_t)(p + i) * 128 + cg * 8];
        const float4 vb = *(const float4*)&cbuf[(size_t)(p + i) * 128 + cg * 8 + 4];
        float y[8];
        y[0] = fmaxf(fmaf(va.x, s0.x, h0.x), 0.f);
        y[1] = fmaxf(fmaf(va.y, s0.y, h0.y), 0.f);
        y[2] = fmaxf(fmaf(va.z, s0.z, h0.z), 0.f);
        y[3] = fmaxf(fmaf(va.w, s0.w, h0.w), 0.f);
        y[4] = fmaxf(fmaf(vb.x, s1.x, h1.x), 0.f);
        y[5] = fmaxf(fmaf(vb.y, s1.y, h1.y), 0.f);
        y[6] = fmaxf(fmaf(vb.z, s1.z, h1.z), 0.f);
        y[7] = fmaxf(fmaf(vb.w, s1.w, h1.w), 0.f);
        half8 hv, lv;
#pragma unroll
        for (int j = 0; j < 8; ++j) {
            const f16 hh = (f16)y[j];
            hv[j] = hh;
            lv[j] = (f16)(y[j] - (float)hh);
        }
        const int pp = pi + i;
        const int h = pp / 56;
        const int w = pp - h * 56;
        const size_t chunk = (size_t)b * PB + (h + 1) * 58 + (w + 1);
        *(half8*)(X2 + ((size_t)cg * PPLANE + chunk) * 16) = hv;
        *(half8*)(X2 + ((size_t)(cg + 16) * PPLANE + chunk) * 16) = lv;
    }
}

// ---------------------------------------------------------------------------
// final: bn2 + residual add + relu, [gp][oc] -> [b][c][hw] via swizzled LDS
// ---------------------------------------------------------------------------
__global__ __launch_bounds__(256) void final_kernel(
        const float* __restrict__ cbuf, const float* __restrict__ stats,
        const float* __restrict__ g, const float* __restrict__ bb,
        const float* __restrict__ resid, float* __restrict__ out) {
    __shared__ float xs[8192];
    __shared__ float scs[128], shs[128];
    const int t = threadIdx.x;
    if (t < 128) {
        const float m = stats[t] * (1.f / NPC);
        const float var = stats[128 + t] * (1.f / NPC) - m * m;
        const float inv = 1.f / sqrtf(var + 1e-5f);
        const float sc = g[t] * inv;
        scs[t] = sc;
        shs[t] = bb[t] - m * sc;
    }
    __syncthreads();
    const int blk = blockIdx.x;                  // 784
#pragma unroll
    for (int i = 0; i < 8; ++i) {
        const int idx = i * 256 + t;
        const int px = idx >> 5;
        const int q = idx & 31;
        const float4 v = *(const float4*)&cbuf[(size_t)(blk * 64 + px) * 128 + q * 4];
        const float vv[4] = {v.x, v.y, v.z, v.w};
#pragma unroll
        for (int j = 0; j < 4; ++j) {
            const int c = q * 4 + j;
            xs[c * 64 + SW(c, px)] = fmaf(vv[j], scs[c], shs[c]);
        }
    }
    __syncthreads();
    const int b = blk / 49;
    const int p0 = (blk - b * 49) * 64;
    const int lane = t & 63, wq = t >> 6;
#pragma unroll
    for (int i = 0; i < 32; ++i) {
        const int c = i * 4 + wq;
        const float v = xs[c * 64 + SW(c, lane)];
        const size_t gi = (size_t)(b * 128 + c) * HW_ + p0 + lane;
        out[gi] = fmaxf(v + resid[gi], 0.f);
    }
}

// ---------------------------------------------------------------------------
extern "C" void kernel_launch(void* const* d_in, const int* in_sizes, int n_in,
                              void* d_out, int out_size, void* d_ws, size_t ws_size,
                              hipStream_t stream) {
    const float* x   = (const float*)d_in[0];
    const float* w1  = (const float*)d_in[1];
    const float* wa1 = (const float*)d_in[2];
    const float* pa1 = (const float*)d_in[3];
    const float* g1  = (const float*)d_in[4];
    const float* b1  = (const float*)d_in[5];
    const float* w2  = (const float*)d_in[6];
    const float* wa2 = (const float*)d_in[7];
    const float* pa2 = (const float*)d_in[8];
    const float* g2  = (const float*)d_in[9];
    const float* b2  = (const float*)d_in[10];
    float* out = (float*)d_out;

    // ws layout (bytes):
    //   X2    @ 0          : 27,557,888  (32 planes * 53824 chunks * 16 B)
    //   cbuf  @ 27,557,888 : 25,690,112
    //   W2a   @ 53,248,000 :    294,912  (+ one extra tap of slack never read)
    //   W2b   @ 53,542,912 :    294,912
    //   stats @ 53,837,824 :      2,048  (stats1 256 f + stats2 256 f)
    char* ws = (char*)d_ws;
    char*  X2    = ws;
    float* cbuf  = (float*)(ws + 27557888);
    f16*   W2a   = (f16*)(ws + 53248000);
    f16*   W2b   = (f16*)(ws + 53542912);
    float* stats = (float*)(ws + 53837824);
    float* stats1 = stats;
    float* stats2 = stats + 256;

    hipLaunchKernelGGL(prep_kernel, dim3(144), dim3(256), 0, stream,
                       w1, wa1, w2, wa2, W2a, W2b);
    hipLaunchKernelGGL(pad_kernel, dim3(456), dim3(256), 0, stream, X2);
    hipLaunchKernelGGL(pack_kernel, dim3(784), dim3(256), 0, stream,
                       x, X2, stats);
    hipLaunchKernelGGL(conv_kernel, dim3(392), dim3(256), 0, stream,
                       X2, (const char*)W2a, wa1, pa1, cbuf, stats1);
    hipLaunchKernelGGL(bn_split_kernel, dim3(784), dim3(256), 0, stream,
                       cbuf, stats1, g1, b1, X2);
    hipLaunchKernelGGL(conv_kernel, dim3(392), dim3(256), 0, stream,
                       X2, (const char*)W2b, wa2, pa2, cbuf, stats2);
    hipLaunchKernelGGL(final_kernel, dim3(784), dim3(256), 0, stream,
                       cbuf, stats2, g2, b2, x, out);
}

// Round 6
// 212.578 us; speedup vs baseline: 1.2592x; 1.2592x over previous
//
#include <hip/hip_runtime.h>
#include <math.h>

typedef _Float16 f16;
typedef _Float16 half8 __attribute__((ext_vector_type(8)));
typedef float floatx16 __attribute__((ext_vector_type(16)));
typedef unsigned int u32;

#define HW_     3136
#define NPC     50176.0f
#define PB      3364            // 58*58 padded pixels per image
#define PPLANE  53824           // 16 images * PB (chunks per k2-plane)
#define ASTRIDE (2 * PPLANE * 16)   // bytes between s-steps (k2 += 2) = 1722368

// LDS scalar swizzle (conflict-free both phases; same as final_kernel, verified)
#define SW(c, px) (((px) + ((c) >> 2) + ((c) & 3) * 8) & 63)

// async 16B global->LDS copy (lane L lands at wave-uniform ldsbase + L*16)
typedef __attribute__((address_space(3))) u32 lds_u32;
typedef __attribute__((address_space(1))) u32 glb_u32;
__device__ __forceinline__ void async_copy16(const void* g, void* l) {
    __builtin_amdgcn_global_load_lds((const glb_u32*)g, (lds_u32*)l, 16, 0, 0);
}

// ---------------------------------------------------------------------------
// prep: quantize weights to integer-valued fp16, packed MFMA-fragment-major:
// chunk (tap*16 + k2)*128 + oc = 8 f16 of channels k2*8..k2*8+7 for one oc
// ---------------------------------------------------------------------------
__global__ __launch_bounds__(256) void prep_kernel(
        const float* __restrict__ w1, const float* __restrict__ wa1,
        const float* __restrict__ w2, const float* __restrict__ wa2,
        f16* __restrict__ W2a, f16* __restrict__ W2b) {
    const int idx = blockIdx.x * 256 + threadIdx.x;    // 0..36863
    const float* w;
    const float* wa;
    f16* o;
    int m;
    if (idx < 18432) { w = w1; wa = wa1; o = W2a; m = idx; }
    else             { w = w2; wa = wa2; o = W2b; m = idx - 18432; }
    const int tap = m >> 11;
    const int r = m & 2047;
    const int k2 = r >> 7;
    const int oc = r & 127;
    const float a = wa[tap];
    const float* src = w + ((size_t)(tap * 128 + oc) * 128 + k2 * 8);
    half8 hv;
#pragma unroll
    for (int j = 0; j < 8; ++j)
        hv[j] = (f16)rintf(fminf(fmaxf(src[j] / a, -4.f), 3.f));
    *(half8*)(o + (size_t)m * 8) = hv;
}

// ---------------------------------------------------------------------------
// pad: zero the spatial border chunks of X2 (all 32 k2-planes, 16 images)
// ---------------------------------------------------------------------------
__global__ __launch_bounds__(256) void pad_kernel(char* __restrict__ X2) {
    const int idx = blockIdx.x * 256 + threadIdx.x;    // 116736 = 32*16*228
    const int k2 = idx / 3648;
    const int r = idx - k2 * 3648;
    const int b = r / 228;
    const int j = r - b * 228;
    int h, w;
    if (j < 58)        { h = 0;  w = j; }
    else if (j < 116)  { h = 57; w = j - 58; }
    else { const int k = j - 116; h = 1 + (k >> 1); w = (k & 1) * 57; }
    const size_t chunk = (size_t)k2 * PPLANE + (size_t)b * PB + h * 58 + w;
    float4 z = {0.f, 0.f, 0.f, 0.f};
    *(float4*)(X2 + chunk * 16) = z;
}

// ---------------------------------------------------------------------------
// pack: x fp32 [b][c][hw] -> X2 hi/lo fp16 chunks [k2][b][hp][wp].
// LDS-free, coalesced both sides: thread owns one pixel (lanes px-minor),
// builds whole 8-channel chunks in registers.
// ---------------------------------------------------------------------------
__global__ __launch_bounds__(256) void pack_kernel(
        const float* __restrict__ x, char* __restrict__ X2,
        float* __restrict__ stats) {
    const int t = threadIdx.x;
    const int blk = blockIdx.x;                 // 784 tiles of 64 px
    if (blk == 0 && t < 512) stats[t] = 0.f;    // zero stats1+stats2
    const int b = blk / 49;
    const int p0 = (blk - b * 49) * 64;
    const int px = t & 63;
    const int cq = t >> 6;
    const int p = p0 + px;
    const int h = p / 56;
    const int w = p - h * 56;
    const size_t pp = (size_t)b * PB + (h + 1) * 58 + (w + 1);
    const float* xb = x + (size_t)b * 128 * HW_ + p;
#pragma unroll
    for (int s = 0; s < 4; ++s) {
        const int cg = s * 4 + cq;              // 0..15
        half8 hv, lv;
#pragma unroll
        for (int j = 0; j < 8; ++j) {
            const float v = xb[(size_t)(cg * 8 + j) * HW_];
            const f16 hh = (f16)v;
            hv[j] = hh;
            lv[j] = (f16)(v - (float)hh);
        }
        *(half8*)(X2 + ((size_t)cg * PPLANE + pp) * 16) = hv;
        *(half8*)(X2 + ((size_t)(cg + 16) * PPLANE + pp) * 16) = lv;
    }
}

// ---------------------------------------------------------------------------
// conv: MFMA split-conv. Block 128px x 128oc, 4 waves 64x64 (2x2).
// A: direct global, 8-deep register rotation w/ cross-tap refill (256cyc look).
// B: LDS double-buffer staged via global_load_lds one tap ahead (no VGPRs);
//    read as 2-deep ds_read_b128 rotation. One barrier per tap = the fence.
// ---------------------------------------------------------------------------
__global__ __launch_bounds__(256, 2) void conv_kernel(
        const char* __restrict__ X2, const char* __restrict__ W2,
        const float* __restrict__ wav, const float* __restrict__ pav,
        float* __restrict__ cbuf, float* __restrict__ stats) {
    __shared__ f16 Bls[2][16384];    // 2 x 32 KB (chunk-major, W2 tap order)
    __shared__ float red[512];
    const int t = threadIdx.x;
    const int lane = t & 63;
    const int wv = t >> 6;
    const int wm = wv & 1, wn = wv >> 1;
    const int tile = (blockIdx.x & 7) * 49 + (blockIdx.x >> 3);  // XCD swizzle
    const int kh = lane >> 5;
    const int ln = lane & 31;

    // pixel bases for the wave's two 32-px m-tiles
    int ppad[2];
#pragma unroll
    for (int mt = 0; mt < 2; ++mt) {
        const int gp = tile * 128 + wm * 64 + mt * 32 + ln;
        const int b = gp / HW_;
        const int p = gp - b * HW_;
        const int h = p / 56;
        const int w = p - h * 56;
        ppad[mt] = b * PB + (h + 1) * 58 + (w + 1);
    }
    // B ds_read byte offset (fragment nt at kf: + kf*4096)
    int bdsoff[2];
#pragma unroll
    for (int nt = 0; nt < 2; ++nt)
        bdsoff[nt] = (kh * 128 + wn * 64 + nt * 32 + ln) * 16;
    // B staging chunk indices (8 wave-insts x 64 lanes = 512 chunks per wave)
    const int sbase = wv * 8;

    floatx16 facc[2][2];
#pragma unroll
    for (int mt = 0; mt < 2; ++mt)
#pragma unroll
        for (int nt = 0; nt < 2; ++nt)
#pragma unroll
            for (int r = 0; r < 16; ++r) facc[mt][nt][r] = 0.f;

    // ---- prologue: stage tap0 B into buf0; fill A chunks 0..7 (tap0) ----
#pragma unroll
    for (int i = 0; i < 8; ++i)
        async_copy16(W2 + (((sbase + i) * 64 + lane) << 4),
                     (void*)&Bls[0][(sbase + i) * 512]);
    int aoff[2], aoffn[2];
#pragma unroll
    for (int mt = 0; mt < 2; ++mt) {
        aoff[mt] = ((ppad[mt] - 59) + kh * PPLANE) << 4;   // tap0: di=-1,dj=-1
        aoffn[mt] = aoff[mt];
    }
    half8 afr[2][8];
#pragma unroll
    for (int s0 = 0; s0 < 8; ++s0)
#pragma unroll
        for (int mt = 0; mt < 2; ++mt)
            afr[mt][s0] = *(const half8*)(X2 + aoff[mt] + s0 * ASTRIDE);
    __syncthreads();    // fences tap0 B staging

    for (int tap = 0; tap < 9; ++tap) {
        const float pak = pav[tap];
        const float s1 = wav[tap] / pak;
        const char* bcur = (const char*)&Bls[tap & 1][0];
        if (tap < 8) {
            // stage next tap's B into the other buffer (fenced by tap-end barrier)
            const char* wt = W2 + (tap + 1) * 32768;
            f16* bnxt = &Bls[(tap + 1) & 1][0];
#pragma unroll
            for (int i = 0; i < 8; ++i)
                async_copy16(wt + (((sbase + i) * 64 + lane) << 4),
                             (void*)&bnxt[(sbase + i) * 512]);
            const int dn = ((tap + 1) % 3 - 1) * 58 + ((tap + 1) / 3 - 1);
#pragma unroll
            for (int mt = 0; mt < 2; ++mt)
                aoffn[mt] = ((ppad[mt] + dn) + kh * PPLANE) << 4;
        }
        // prefill B slots for steps 0,1 (current buffer valid since last barrier)
        half8 bds[2][2];
#pragma unroll
        for (int nt = 0; nt < 2; ++nt)
#pragma unroll
            for (int sl = 0; sl < 2; ++sl)
                bds[nt][sl] = *(const half8*)(bcur + sl * 4096 + bdsoff[nt]);

        floatx16 acc[2][2];
#pragma unroll
        for (int mt = 0; mt < 2; ++mt)
#pragma unroll
            for (int nt = 0; nt < 2; ++nt)
#pragma unroll
                for (int r = 0; r < 16; ++r) acc[mt][nt][r] = 0.f;

#pragma unroll
        for (int s = 0; s < 16; ++s) {
#pragma unroll
            for (int nt = 0; nt < 2; ++nt)
#pragma unroll
                for (int mt = 0; mt < 2; ++mt)
                    acc[mt][nt] = __builtin_amdgcn_mfma_f32_32x32x16_f16(
                        afr[mt][s & 7], bds[nt][s & 1], acc[mt][nt], 0, 0, 0);
            // B rotation refill (current buffer only; steps 14,15 pre-written)
            if (s <= 13) {
                const int kf2 = (s + 2) & 7;
#pragma unroll
                for (int nt = 0; nt < 2; ++nt)
                    bds[nt][s & 1] =
                        *(const half8*)(bcur + kf2 * 4096 + bdsoff[nt]);
            }
            // A rotation refill: within-tap chunks 8..15, then next tap 0..7
            if (s < 8) {
#pragma unroll
                for (int mt = 0; mt < 2; ++mt)
                    afr[mt][s & 7] =
                        *(const half8*)(X2 + aoff[mt] + (s + 8) * ASTRIDE);
            } else if (tap < 8) {
#pragma unroll
                for (int mt = 0; mt < 2; ++mt)
                    afr[mt][s & 7] =
                        *(const half8*)(X2 + aoffn[mt] + (s - 8) * ASTRIDE);
            }
        }

        // per-tap 8-bit LSQ quantize of the partial sum, accumulate
#pragma unroll
        for (int mt = 0; mt < 2; ++mt)
#pragma unroll
            for (int nt = 0; nt < 2; ++nt)
#pragma unroll
                for (int r = 0; r < 16; ++r) {
                    const float q =
                        rintf(fminf(fmaxf(acc[mt][nt][r] * s1, -128.f), 127.f));
                    facc[mt][nt][r] = fmaf(q, pak, facc[mt][nt][r]);
                }
        aoff[0] = aoffn[0];
        aoff[1] = aoffn[1];
        __syncthreads();   // all reads of buf[tap&1] done; fences next-B staging
    }

    // epilogue: cbuf [gp][oc] fp32  (32x32 C/D: row=(r&3)+8*(r>>2)+4*kh, col=ln)
    const int gpb = tile * 128 + wm * 64;
    const int ocb = wn * 64 + ln;
#pragma unroll
    for (int mt = 0; mt < 2; ++mt)
#pragma unroll
        for (int r = 0; r < 16; ++r) {
            const int row = (r & 3) + 8 * (r >> 2) + 4 * kh;
            const int gp = gpb + mt * 32 + row;
            float* rp = cbuf + (size_t)gp * 128 + ocb;
            rp[0]  = facc[mt][0][r];
            rp[32] = facc[mt][1][r];
        }

    // fused BN stats
    float sv[2], qv[2];
#pragma unroll
    for (int nt = 0; nt < 2; ++nt) {
        float s = 0.f, q = 0.f;
#pragma unroll
        for (int mt = 0; mt < 2; ++mt)
#pragma unroll
            for (int r = 0; r < 16; ++r) {
                const float v = facc[mt][nt][r];
                s += v;
                q = fmaf(v, v, q);
            }
        s += __shfl_xor(s, 32, 64);
        q += __shfl_xor(q, 32, 64);
        sv[nt] = s; qv[nt] = q;
    }
    if (lane < 32) {
#pragma unroll
        for (int nt = 0; nt < 2; ++nt) {
            const int oc = wn * 64 + nt * 32 + lane;
            red[oc * 2 + wm] = sv[nt];
            red[256 + oc * 2 + wm] = qv[nt];
        }
    }
    __syncthreads();
    if (t < 128) {
        atomicAdd(&stats[t],       red[2 * t] + red[2 * t + 1]);
        atomicAdd(&stats[128 + t], red[256 + 2 * t] + red[256 + 2 * t + 1]);
    }
}

// ---------------------------------------------------------------------------
// bn_split: cbuf fp32 [gp][oc] -> bn+relu -> X2 hi/lo packed (conv2 input).
// Coalesced reads, conflict-free LDS transpose, coalesced chunk writes.
// ---------------------------------------------------------------------------
__global__ __launch_bounds__(256) void bn_split_kernel(
        const float* __restrict__ cbuf, const float* __restrict__ stats,
        const float* __restrict__ g, const float* __restrict__ bb,
        char* __restrict__ X2) {
    __shared__ float xs[8192];
    __shared__ float scs[128], shs[128];
    const int t = threadIdx.x;
    if (t < 128) {
        const float m = stats[t] * (1.f / NPC);
        const float var = stats[128 + t] * (1.f / NPC) - m * m;
        const float inv = 1.f / sqrtf(var + 1e-5f);
        const float sc = g[t] * inv;
        scs[t] = sc;
        shs[t] = bb[t] - m * sc;
    }
    __syncthreads();
    const int blk = blockIdx.x;                  // 784
#pragma unroll
    for (int i = 0; i < 8; ++i) {
        const int idx = i * 256 + t;
        const int px = idx >> 5;
        const int q = idx & 31;
        const float4 v = *(const float4*)&cbuf[(size_t)(blk * 64 + px) * 128 + q * 4];
        const float vv[4] = {v.x, v.y, v.z, v.w};
#pragma unroll
        for (int j = 0; j < 4; ++j) {
            const int c = q * 4 + j;
            xs[c * 64 + SW(c, px)] = fmaxf(fmaf(vv[j], scs[c], shs[c]), 0.f);
        }
    }
    __syncthreads();
    const int b = blk / 49;
    const int p0 = (blk - b * 49) * 64;
    const int px = t & 63;
    const int cq = t >> 6;
    const int p = p0 + px;
    const int h = p / 56;
    const int w = p - h * 56;
    const size_t pp = (size_t)b * PB + (h + 1) * 58 + (w + 1);
#pragma unroll
    for (int s = 0; s < 4; ++s) {
        const int cg = s * 4 + cq;
        half8 hv, lv;
#pragma unroll
        for (int j = 0; j < 8; ++j) {
            const int c = cg * 8 + j;
            const float v = xs[c * 64 + SW(c, px)];
            const f16 hh = (f16)v;
            hv[j] = hh;
            lv[j] = (f16)(v - (float)hh);
        }
        *(half8*)(X2 + ((size_t)cg * PPLANE + pp) * 16) = hv;
        *(half8*)(X2 + ((size_t)(cg + 16) * PPLANE + pp) * 16) = lv;
    }
}

// ---------------------------------------------------------------------------
// final: bn2 + residual add + relu, [gp][oc] -> [b][c][hw] via swizzled LDS
// ---------------------------------------------------------------------------
__global__ __launch_bounds__(256) void final_kernel(
        const float* __restrict__ cbuf, const float* __restrict__ stats,
        const float* __restrict__ g, const float* __restrict__ bb,
        const float* __restrict__ resid, float* __restrict__ out) {
    __shared__ float xs[8192];
    __shared__ float scs[128], shs[128];
    const int t = threadIdx.x;
    if (t < 128) {
        const float m = stats[t] * (1.f / NPC);
        const float var = stats[128 + t] * (1.f / NPC) - m * m;
        const float inv = 1.f / sqrtf(var + 1e-5f);
        const float sc = g[t] * inv;
        scs[t] = sc;
        shs[t] = bb[t] - m * sc;
    }
    __syncthreads();
    const int blk = blockIdx.x;                  // 784
#pragma unroll
    for (int i = 0; i < 8; ++i) {
        const int idx = i * 256 + t;
        const int px = idx >> 5;
        const int q = idx & 31;
        const float4 v = *(const float4*)&cbuf[(size_t)(blk * 64 + px) * 128 + q * 4];
        const float vv[4] = {v.x, v.y, v.z, v.w};
#pragma unroll
        for (int j = 0; j < 4; ++j) {
            const int c = q * 4 + j;
            xs[c * 64 + SW(c, px)] = fmaf(vv[j], scs[c], shs[c]);
        }
    }
    __syncthreads();
    const int b = blk / 49;
    const int p0 = (blk - b * 49) * 64;
    const int lane = t & 63, wq = t >> 6;
#pragma unroll
    for (int i = 0; i < 32; ++i) {
        const int c = i * 4 + wq;
        const float v = xs[c * 64 + SW(c, lane)];
        const size_t gi = (size_t)(b * 128 + c) * HW_ + p0 + lane;
        out[gi] = fmaxf(v + resid[gi], 0.f);
    }
}

// ---------------------------------------------------------------------------
extern "C" void kernel_launch(void* const* d_in, const int* in_sizes, int n_in,
                              void* d_out, int out_size, void* d_ws, size_t ws_size,
                              hipStream_t stream) {
    const float* x   = (const float*)d_in[0];
    const float* w1  = (const float*)d_in[1];
    const float* wa1 = (const float*)d_in[2];
    const float* pa1 = (const float*)d_in[3];
    const float* g1  = (const float*)d_in[4];
    const float* b1  = (const float*)d_in[5];
    const float* w2  = (const float*)d_in[6];
    const float* wa2 = (const float*)d_in[7];
    const float* pa2 = (const float*)d_in[8];
    const float* g2  = (const float*)d_in[9];
    const float* b2  = (const float*)d_in[10];
    float* out = (float*)d_out;

    // ws layout (bytes):
    //   X2    @ 0          : 27,557,888  (32 planes * 53824 chunks * 16 B)
    //   cbuf  @ 27,557,888 : 25,690,112
    //   W2a   @ 53,248,000 :    294,912
    //   W2b   @ 53,542,912 :    294,912
    //   stats @ 53,837,824 :      2,048  (stats1 256 f + stats2 256 f)
    char* ws = (char*)d_ws;
    char*  X2    = ws;
    float* cbuf  = (float*)(ws + 27557888);
    f16*   W2a   = (f16*)(ws + 53248000);
    f16*   W2b   = (f16*)(ws + 53542912);
    float* stats = (float*)(ws + 53837824);
    float* stats1 = stats;
    float* stats2 = stats + 256;

    hipLaunchKernelGGL(prep_kernel, dim3(144), dim3(256), 0, stream,
                       w1, wa1, w2, wa2, W2a, W2b);
    hipLaunchKernelGGL(pad_kernel, dim3(456), dim3(256), 0, stream, X2);
    hipLaunchKernelGGL(pack_kernel, dim3(784), dim3(256), 0, stream,
                       x, X2, stats);
    hipLaunchKernelGGL(conv_kernel, dim3(392), dim3(256), 0, stream,
                       X2, (const char*)W2a, wa1, pa1, cbuf, stats1);
    hipLaunchKernelGGL(bn_split_kernel, dim3(784), dim3(256), 0, stream,
                       cbuf, stats1, g1, b1, X2);
    hipLaunchKernelGGL(conv_kernel, dim3(392), dim3(256), 0, stream,
                       X2, (const char*)W2b, wa2, pa2, cbuf, stats2);
    hipLaunchKernelGGL(final_kernel, dim3(784), dim3(256), 0, stream,
                       cbuf, stats2, g2, b2, x, out);
}